// Round 6
// baseline (56.149 us; speedup 1.0000x reference)
//
#include <hip/hip_runtime.h>

#define N_TASKS 16
#define LMAX 64
#define ROWS_PER_BLOCK 512          // 512 rows * 16 float4 = 8192 float4 per block
#define F4_PER_BLOCK (ROWS_PER_BLOCK * 16)
#define ITERS (F4_PER_BLOCK / 256)  // 32

typedef float f32x4 __attribute__((ext_vector_type(4)));
typedef float f32x2 __attribute__((ext_vector_type(2)));

__global__ __launch_bounds__(256) void MultiElementWiseAffine_kernel(
    const float* __restrict__ input,      // [B]
    const int*   __restrict__ task_ids,   // [B]
    const float* __restrict__ offsets,    // [N_TASKS*LMAX]
    const float* __restrict__ disc,       // [N_TASKS*LMAX]
    const int*   __restrict__ lengths,    // [N_TASKS]
    f32x4*       __restrict__ out,        // [B*16] float4 view of [B][64]
    int total4)                           // B*16
{
    // Per-task table: [t][0..63] = masked disc (m), [t][64..127] = m*offset.
    __shared__ alignas(16) float s_tab[N_TASKS * 128];
    // Per-row data for this block's 512 rows: {x, bitcast(task)}.
    __shared__ alignas(8) f32x2 s_row[ROWS_PER_BLOCK];

    const int tid    = threadIdx.x;
    const int n_rows = total4 >> 4;
    const int row0   = blockIdx.x * ROWS_PER_BLOCK;

    for (int i = tid; i < N_TASKS * LMAX; i += 256) {
        int t = i >> 6, k = i & (LMAX - 1);
        float m = (k < lengths[t]) ? disc[i] : 0.0f;
        s_tab[t * 128 + k]      = m;
        s_tab[t * 128 + 64 + k] = m * offsets[i];
    }
    for (int i = tid; i < ROWS_PER_BLOCK; i += 256) {
        int r = row0 + i;
        f32x2 v;
        v.x = (r < n_rows) ? input[r] : 0.0f;
        v.y = __int_as_float((r < n_rows) ? task_ids[r] : 0);
        s_row[i] = v;
    }
    __syncthreads();

    const int  k4    = tid & 15;        // loop-invariant float4-within-row
    const int  lr0   = tid >> 4;        // local row at iteration 0
    const long gbase = (long)blockIdx.x * F4_PER_BLOCK + tid;

    if (gbase + (ITERS - 1) * 256 < total4) {
        // Full block: fully unrolled, all LDS row reads use immediate offsets,
        // only VMEM inst per iteration is the dense nt store.
        #pragma unroll
        for (int it = 0; it < ITERS; ++it) {
            f32x2 rv = s_row[lr0 + it * 16];        // ds_read_b64, imm offset
            float x  = rv.x;
            int   t  = __float_as_int(rv.y);
            const float* base = &s_tab[t * 128 + (k4 << 2)];
            f32x4 mv = *(const f32x4*)(base);       // ds_read_b128
            f32x4 pv = *(const f32x4*)(base + 64);  // ds_read_b128 offset:256
            f32x4 r;
            r.x = fmaf(mv.x, x, pv.x);
            r.y = fmaf(mv.y, x, pv.y);
            r.z = fmaf(mv.z, x, pv.z);
            r.w = fmaf(mv.w, x, pv.w);
            __builtin_nontemporal_store(r, &out[gbase + it * 256]);
        }
    } else {
        for (int it = 0; it < ITERS; ++it) {
            long g = gbase + it * 256;
            if (g >= total4) break;
            f32x2 rv = s_row[lr0 + it * 16];
            float x  = rv.x;
            int   t  = __float_as_int(rv.y);
            const float* base = &s_tab[t * 128 + (k4 << 2)];
            f32x4 mv = *(const f32x4*)(base);
            f32x4 pv = *(const f32x4*)(base + 64);
            f32x4 r;
            r.x = fmaf(mv.x, x, pv.x);
            r.y = fmaf(mv.y, x, pv.y);
            r.z = fmaf(mv.z, x, pv.z);
            r.w = fmaf(mv.w, x, pv.w);
            __builtin_nontemporal_store(r, &out[g]);
        }
    }
}

extern "C" void kernel_launch(void* const* d_in, const int* in_sizes, int n_in,
                              void* d_out, int out_size, void* d_ws, size_t ws_size,
                              hipStream_t stream) {
    const float* input    = (const float*)d_in[0];
    const int*   task_ids = (const int*)d_in[1];
    const float* offsets  = (const float*)d_in[2];
    const float* disc     = (const float*)d_in[3];
    const int*   lengths  = (const int*)d_in[4];
    f32x4*       out      = (f32x4*)d_out;

    int total4 = out_size / 4;                       // B * 16
    int grid   = (total4 + F4_PER_BLOCK - 1) / F4_PER_BLOCK;  // 2048 for B=1M

    MultiElementWiseAffine_kernel<<<grid, 256, 0, stream>>>(
        input, task_ids, offsets, disc, lengths, out, total4);
}